// Round 7
// baseline (2353.800 us; speedup 1.0000x reference)
//
#include <hip/hip_runtime.h>

typedef unsigned int u32;

#define NNODES 100000
#define NEDGES 600000
#define CC 16
#define HH 48
#define NL 5

// ---- ws layout (float units): x1 [0,1.6M) ; x2 [1.6M,3.2M) ; cnt [3.2M,3.3M) ; sl [3.3M]
#define OX1 0
#define OX2 1600000
#define OCNT 3200000
#define OSL 3300000
#define WS_NEED_FLOATS 3300032

// ================= NodeConv: per-edge MLP (33->16, 5x 16->16), atomic mean-scatter ======
__global__ __launch_bounds__(256) void nc_kernel(
    const float* __restrict__ x, const int* __restrict__ ei,
    const float* __restrict__ ang,
    const float* __restrict__ w0, const float* __restrict__ b0,
    const float* __restrict__ wh, const float* __restrict__ bh,
    float* __restrict__ agg, float* __restrict__ cnt)
{
  int e = blockIdx.x * 256 + threadIdx.x;
  if (e >= NEDGES) return;
  int s = ei[e];
  int d = ei[NEDGES + e];

  float in[33];
  {
    const float4* pd = (const float4*)(x + (long)d * 16);
    const float4* ps = (const float4*)(x + (long)s * 16);
    #pragma unroll
    for (int i = 0; i < 4; i++){ float4 v = pd[i]; in[4*i]=v.x; in[4*i+1]=v.y; in[4*i+2]=v.z; in[4*i+3]=v.w; }
    #pragma unroll
    for (int i = 0; i < 4; i++){ float4 v = ps[i]; in[16+4*i]=v.x; in[16+4*i+1]=v.y; in[16+4*i+2]=v.z; in[16+4*i+3]=v.w; }
  }
  in[32] = ang[e];

  float h[16], acc[16];
  #pragma unroll
  for (int j = 0; j < 16; j++) acc[j] = b0[j];
  #pragma unroll
  for (int k = 0; k < 33; k++){
    float v = in[k];
    #pragma unroll
    for (int j = 0; j < 16; j++) acc[j] = fmaf(v, w0[k*16+j], acc[j]);
  }
  #pragma unroll
  for (int j = 0; j < 16; j++) h[j] = fmaxf(acc[j], 0.f);

  for (int l = 0; l < NL; l++){
    const float* w = wh + l * 256;
    const float* b = bh + l * 16;
    #pragma unroll
    for (int j = 0; j < 16; j++) acc[j] = b[j];
    #pragma unroll
    for (int k = 0; k < 16; k++){
      float v = h[k];
      #pragma unroll
      for (int j = 0; j < 16; j++) acc[j] = fmaf(v, w[k*16+j], acc[j]);
    }
    #pragma unroll
    for (int j = 0; j < 16; j++) h[j] = fmaxf(acc[j], 0.f);
  }

  float* ag = agg + (long)d * 16;
  #pragma unroll
  for (int j = 0; j < 16; j++) atomicAdd(ag + j, h[j]);
  atomicAdd(cnt + d, 1.0f);
}

// ================= mean finalize in place ==================
__global__ __launch_bounds__(256) void node_fin(float* __restrict__ x, const float* __restrict__ cnt)
{
  int i = blockIdx.x * 256 + threadIdx.x;
  if (i >= NNODES * CC) return;
  float c = cnt[i >> 4];
  x[i] = x[i] / fmaxf(c, 1.f);
}

// ===== dense layer: h (LDS, stride-49 slice) x W (uniform/scalar) -> back to LDS =====
template<int IN>
__device__ __forceinline__ void dense_to_lds(float* hl,
    const float* __restrict__ w, const float* __restrict__ b)
{
  float acc[HH];
  #pragma unroll
  for (int j = 0; j < HH; j++) acc[j] = b[j];
  #pragma unroll 8
  for (int k = 0; k < IN; k++){
    float v = hl[k];                          // ds_read_b32, stride 49 -> conflict-free
    #pragma unroll
    for (int j = 0; j < HH; j++) acc[j] = fmaf(v, w[k*HH + j], acc[j]);  // scalar weight
  }
  #pragma unroll
  for (int j = 0; j < HH; j++) hl[j] = fmaxf(acc[j], 0.f);
}

__device__ __forceinline__ void loadpair(const float* __restrict__ x, int a, int b, float* hl){
  const float4* pa = (const float4*)(x + (long)a * 16);
  const float4* pb = (const float4*)(x + (long)b * 16);
  #pragma unroll
  for (int i = 0; i < 4; i++){ float4 v = pa[i]; hl[4*i]=v.x; hl[4*i+1]=v.y; hl[4*i+2]=v.z; hl[4*i+3]=v.w; }
  #pragma unroll
  for (int i = 0; i < 4; i++){ float4 v = pb[i]; hl[16+4*i]=v.x; hl[16+4*i+1]=v.y; hl[16+4*i+2]=v.z; hl[16+4*i+3]=v.w; }
}

// ================= fused EdgeConv1 + EdgeConv2 (ef in registers, FP32 OUTPUT) ==========
__global__ __launch_bounds__(256) void ec_kernel(
    const float* __restrict__ x1, const float* __restrict__ x2,
    const int* __restrict__ ei, const float* __restrict__ act,
    const float* __restrict__ e1w0, const float* __restrict__ e1b0,
    const float* __restrict__ e1wh, const float* __restrict__ e1bh,
    const float* __restrict__ e1wc, const float* __restrict__ e1bc,
    const float* __restrict__ e2w0, const float* __restrict__ e2b0,
    const float* __restrict__ e2wh, const float* __restrict__ e2bh,
    const float* __restrict__ e2wc, const float* __restrict__ e2bc,
    float* __restrict__ out, float* __restrict__ slacc)
{
  __shared__ float hbuf[256 * 49];   // 50,176 B
  float* hl = hbuf + threadIdx.x * 49;

  int e = blockIdx.x * 256 + threadIdx.x;
  bool valid = e < NEDGES;
  int e0 = valid ? e : (NEDGES - 1);
  int s = ei[e0];
  int d = ei[NEDGES + e0];

  float f1[HH], ef[HH];
  float side = 0.f;

  // ======== EdgeConv1 on x1 ========
  loadpair(x1, d, s, hl);                         // f1 = MLP([x_dst, x_src])
  dense_to_lds<32>(hl, e1w0, e1b0);
  for (int l = 0; l < NL; l++) dense_to_lds<48>(hl, e1wh + l*2304, e1bh + l*48);
  #pragma unroll
  for (int j = 0; j < HH; j++) f1[j] = hl[j];

  loadpair(x1, s, d, hl);                         // f2 = MLP([x_src, x_dst])
  dense_to_lds<32>(hl, e1w0, e1b0);
  for (int l = 0; l < NL; l++) dense_to_lds<48>(hl, e1wh + l*2304, e1bh + l*48);

  #pragma unroll
  for (int j = 0; j < HH; j++){
    float f2v = hl[j];
    float dd = f1[j] - f2v;
    side += dd * dd;
    hl[j] = 0.5f * (f1[j] + f2v);                 // fe -> LDS for combine
  }
  {
    float a = act[e0];
    float acc[HH];
    #pragma unroll
    for (int j = 0; j < HH; j++) acc[j] = fmaf(a, e1wc[48*HH + j], e1bc[j]);
    #pragma unroll 8
    for (int k = 0; k < HH; k++){
      float v = hl[k];
      #pragma unroll
      for (int j = 0; j < HH; j++) acc[j] = fmaf(v, e1wc[k*HH + j], acc[j]);
    }
    #pragma unroll
    for (int j = 0; j < HH; j++) ef[j] = acc[j];
  }

  // ======== EdgeConv2 on x2 ========
  loadpair(x2, d, s, hl);
  dense_to_lds<32>(hl, e2w0, e2b0);
  for (int l = 0; l < NL; l++) dense_to_lds<48>(hl, e2wh + l*2304, e2bh + l*48);
  #pragma unroll
  for (int j = 0; j < HH; j++) f1[j] = hl[j];

  loadpair(x2, s, d, hl);
  dense_to_lds<32>(hl, e2w0, e2b0);
  for (int l = 0; l < NL; l++) dense_to_lds<48>(hl, e2wh + l*2304, e2bh + l*48);

  float o = e2bc[0];
  #pragma unroll
  for (int j = 0; j < HH; j++){
    float f2v = hl[j];
    float dd = f1[j] - f2v;
    side += dd * dd;
    float fe = 0.5f * (f1[j] + f2v);
    o = fmaf(fe, e2wc[j], o);
    o = fmaf(ef[j], e2wc[48 + j], o);
  }
  if (valid) out[e0] = o;                          // FP32 store (reference output dtype)

  if (!valid) side = 0.f;
  #pragma unroll
  for (int off = 32; off > 0; off >>= 1) side += __shfl_down(side, off);
  if ((threadIdx.x & 63) == 0) atomicAdd(slacc, side);
}

__global__ void fin_sl(const float* __restrict__ slacc, float* __restrict__ out){
  if (threadIdx.x == 0 && blockIdx.x == 0)
    out[NEDGES] = slacc[0] * (1.0f / 57600000.0f);  // (sum1+sum2)/(2*E*48), fp32
}

// ================= launch ==================
extern "C" void kernel_launch(void* const* d_in, const int* in_sizes, int n_in,
                              void* d_out, int out_size, void* d_ws, size_t ws_size,
                              hipStream_t stream)
{
  if (n_in < 25) return;
  if (ws_size < (size_t)WS_NEED_FLOATS * sizeof(float)) return;

  const float* nf  = (const float*)d_in[0];
  const int*   ei  = (const int*)d_in[1];
  const float* ang = (const float*)d_in[2];
  const float* act = (const float*)d_in[4];
  const float* nc1_w0 = (const float*)d_in[5];
  const float* nc1_b0 = (const float*)d_in[6];
  const float* nc1_wh = (const float*)d_in[7];
  const float* nc1_bh = (const float*)d_in[8];
  const float* nc2_w0 = (const float*)d_in[9];
  const float* nc2_b0 = (const float*)d_in[10];
  const float* nc2_wh = (const float*)d_in[11];
  const float* nc2_bh = (const float*)d_in[12];
  const float* e1w0 = (const float*)d_in[13];
  const float* e1b0 = (const float*)d_in[14];
  const float* e1wh = (const float*)d_in[15];
  const float* e1bh = (const float*)d_in[16];
  const float* e1wc = (const float*)d_in[17];
  const float* e1bc = (const float*)d_in[18];
  const float* e2w0 = (const float*)d_in[19];
  const float* e2b0 = (const float*)d_in[20];
  const float* e2wh = (const float*)d_in[21];
  const float* e2bh = (const float*)d_in[22];
  const float* e2wc = (const float*)d_in[23];
  const float* e2bc = (const float*)d_in[24];

  float* ws  = (float*)d_ws;
  float* x1  = ws + OX1;
  float* x2  = ws + OX2;
  float* cnt = ws + OCNT;
  float* sl  = ws + OSL;
  float* out = (float*)d_out;

  // zero x1, x2, cnt, sl (contiguous)
  hipMemsetAsync(ws, 0, (size_t)WS_NEED_FLOATS * sizeof(float), stream);

  const int eb = (NEDGES + 255) / 256;       // 2344
  const int nb = (NNODES * CC + 255) / 256;  // 6250

  // NodeConv1: nf -> x1 (agg in place), finalize
  hipLaunchKernelGGL(nc_kernel, dim3(eb), dim3(256), 0, stream,
      nf, ei, ang, nc1_w0, nc1_b0, nc1_wh, nc1_bh, x1, cnt);
  hipLaunchKernelGGL(node_fin, dim3(nb), dim3(256), 0, stream, x1, cnt);

  hipMemsetAsync(cnt, 0, (size_t)NNODES * sizeof(float), stream);

  // NodeConv2: x1 -> x2
  hipLaunchKernelGGL(nc_kernel, dim3(eb), dim3(256), 0, stream,
      x1, ei, ang, nc2_w0, nc2_b0, nc2_wh, nc2_bh, x2, cnt);
  hipLaunchKernelGGL(node_fin, dim3(nb), dim3(256), 0, stream, x2, cnt);

  // fused EdgeConv1 + EdgeConv2, fp32 output
  hipLaunchKernelGGL(ec_kernel, dim3(eb), dim3(256), 0, stream,
      x1, x2, ei, act,
      e1w0, e1b0, e1wh, e1bh, e1wc, e1bc,
      e2w0, e2b0, e2wh, e2bh, e2wc, e2bc,
      out, sl);
  hipLaunchKernelGGL(fin_sl, dim3(1), dim3(64), 0, stream, sl, out);
}

// Round 8
// 1763.334 us; speedup vs baseline: 1.3349x; 1.3349x over previous
//
#include <hip/hip_runtime.h>

typedef unsigned int u32;

#define NNODES 100000
#define NEDGES 600000
#define CC 16
#define HH 48
#define NL 5

// ---- CSR ws layout (float-sized units), total 4,000,064 floats = 16.0 MB ----
#define OX1   0          // 1,600,000 f
#define OX2   1600000    // 1,600,000 f
#define OROW  3200000    // 100,001 int
#define ODEG  3300032    // 100,000 int
#define OPERM 3400032    // 600,000 int
#define OSL   4000032    // 1 f
#define WS_CSR_FLOATS    4000064
// ---- fallback (round-7 atomic) layout: 3,300,032 floats = 13.2 MB ----
#define FCNT  3200000
#define FSL   3300000
#define WS_ATOM_FLOATS   3300032

// =================== CSR build ===================
__global__ __launch_bounds__(256) void count_deg(const int* __restrict__ ei, int* __restrict__ deg){
  int e = blockIdx.x * 256 + threadIdx.x;
  if (e >= NEDGES) return;
  atomicAdd(&deg[ei[NEDGES + e]], 1);
}

// exclusive scan of deg[0..NN) -> rowptr[0..NN], single block of 1024
__global__ __launch_bounds__(1024) void scan_deg(const int* __restrict__ deg, int* __restrict__ rowptr){
  __shared__ int part[1024];
  int t = threadIdx.x;
  const int CH = (NNODES + 1023) / 1024;       // 98
  int b = t * CH;
  int e = b + CH < NNODES ? b + CH : NNODES;
  int s = 0;
  for (int i = b; i < e; i++) s += deg[i];
  part[t] = s;
  __syncthreads();
  for (int off = 1; off < 1024; off <<= 1){
    int v = (t >= off) ? part[t - off] : 0;
    __syncthreads();
    part[t] += v;
    __syncthreads();
  }
  int run = (t == 0) ? 0 : part[t - 1];
  for (int i = b; i < e; i++){ rowptr[i] = run; run += deg[i]; }
  if (t == 1023) rowptr[NNODES] = run;         // empty tail chunk -> run = total
}

__global__ __launch_bounds__(256) void scatter_perm(const int* __restrict__ ei,
    const int* __restrict__ rowptr, int* __restrict__ deg2, int* __restrict__ perm){
  int e = blockIdx.x * 256 + threadIdx.x;
  if (e >= NEDGES) return;
  int d = ei[NEDGES + e];
  int pos = rowptr[d] + atomicAdd(&deg2[d], 1);
  perm[pos] = e;
}

// ============ NodeConv, node-parallel (no atomics): per-dst loop over CSR edges ============
__global__ __launch_bounds__(256) void nc_csr(
    const float* __restrict__ x, const int* __restrict__ ei,
    const float* __restrict__ ang,
    const int* __restrict__ rowptr, const int* __restrict__ perm,
    const float* __restrict__ w0, const float* __restrict__ b0,
    const float* __restrict__ wh, const float* __restrict__ bh,
    float* __restrict__ xout)
{
  int n = blockIdx.x * 256 + threadIdx.x;
  if (n >= NNODES) return;
  int beg = rowptr[n], end = rowptr[n + 1];

  float xd[16];
  {
    const float4* pd = (const float4*)(x + (long)n * 16);
    #pragma unroll
    for (int i = 0; i < 4; i++){ float4 v = pd[i]; xd[4*i]=v.x; xd[4*i+1]=v.y; xd[4*i+2]=v.z; xd[4*i+3]=v.w; }
  }
  // layer-0 partial from x[dst] (same for every edge of this node)
  float p0[16];
  #pragma unroll
  for (int j = 0; j < 16; j++) p0[j] = b0[j];
  #pragma unroll
  for (int k = 0; k < 16; k++){
    float v = xd[k];
    #pragma unroll
    for (int j = 0; j < 16; j++) p0[j] = fmaf(v, w0[k*16 + j], p0[j]);
  }

  float sum[16];
  #pragma unroll
  for (int j = 0; j < 16; j++) sum[j] = 0.f;

  for (int idx = beg; idx < end; idx++){
    int e = perm[idx];
    int s = ei[e];
    float a_ = ang[e];
    float xs[16];
    {
      const float4* ps = (const float4*)(x + (long)s * 16);
      #pragma unroll
      for (int i = 0; i < 4; i++){ float4 v = ps[i]; xs[4*i]=v.x; xs[4*i+1]=v.y; xs[4*i+2]=v.z; xs[4*i+3]=v.w; }
    }
    float acc[16], h[16];
    #pragma unroll
    for (int j = 0; j < 16; j++) acc[j] = p0[j];
    #pragma unroll
    for (int k = 0; k < 16; k++){
      float v = xs[k];
      #pragma unroll
      for (int j = 0; j < 16; j++) acc[j] = fmaf(v, w0[(16 + k)*16 + j], acc[j]);
    }
    #pragma unroll
    for (int j = 0; j < 16; j++) h[j] = fmaxf(fmaf(a_, w0[32*16 + j], acc[j]), 0.f);

    for (int l = 0; l < NL; l++){
      const float* w = wh + l * 256;
      const float* b = bh + l * 16;
      #pragma unroll
      for (int j = 0; j < 16; j++) acc[j] = b[j];
      #pragma unroll
      for (int k = 0; k < 16; k++){
        float v = h[k];
        #pragma unroll
        for (int j = 0; j < 16; j++) acc[j] = fmaf(v, w[k*16 + j], acc[j]);
      }
      #pragma unroll
      for (int j = 0; j < 16; j++) h[j] = fmaxf(acc[j], 0.f);
    }
    #pragma unroll
    for (int j = 0; j < 16; j++) sum[j] += h[j];
  }

  float inv = 1.f / fmaxf((float)(end - beg), 1.f);
  float4* po = (float4*)(xout + (long)n * 16);
  #pragma unroll
  for (int i = 0; i < 4; i++){
    float4 v; v.x = sum[4*i]*inv; v.y = sum[4*i+1]*inv; v.z = sum[4*i+2]*inv; v.w = sum[4*i+3]*inv;
    po[i] = v;
  }
}

// =================== fallback round-7 atomic NodeConv ===================
__global__ __launch_bounds__(256) void nc_kernel(
    const float* __restrict__ x, const int* __restrict__ ei,
    const float* __restrict__ ang,
    const float* __restrict__ w0, const float* __restrict__ b0,
    const float* __restrict__ wh, const float* __restrict__ bh,
    float* __restrict__ agg, float* __restrict__ cnt)
{
  int e = blockIdx.x * 256 + threadIdx.x;
  if (e >= NEDGES) return;
  int s = ei[e];
  int d = ei[NEDGES + e];
  float in[33];
  {
    const float4* pd = (const float4*)(x + (long)d * 16);
    const float4* ps = (const float4*)(x + (long)s * 16);
    #pragma unroll
    for (int i = 0; i < 4; i++){ float4 v = pd[i]; in[4*i]=v.x; in[4*i+1]=v.y; in[4*i+2]=v.z; in[4*i+3]=v.w; }
    #pragma unroll
    for (int i = 0; i < 4; i++){ float4 v = ps[i]; in[16+4*i]=v.x; in[16+4*i+1]=v.y; in[16+4*i+2]=v.z; in[16+4*i+3]=v.w; }
  }
  in[32] = ang[e];
  float h[16], acc[16];
  #pragma unroll
  for (int j = 0; j < 16; j++) acc[j] = b0[j];
  #pragma unroll
  for (int k = 0; k < 33; k++){
    float v = in[k];
    #pragma unroll
    for (int j = 0; j < 16; j++) acc[j] = fmaf(v, w0[k*16+j], acc[j]);
  }
  #pragma unroll
  for (int j = 0; j < 16; j++) h[j] = fmaxf(acc[j], 0.f);
  for (int l = 0; l < NL; l++){
    const float* w = wh + l * 256;
    const float* b = bh + l * 16;
    #pragma unroll
    for (int j = 0; j < 16; j++) acc[j] = b[j];
    #pragma unroll
    for (int k = 0; k < 16; k++){
      float v = h[k];
      #pragma unroll
      for (int j = 0; j < 16; j++) acc[j] = fmaf(v, w[k*16+j], acc[j]);
    }
    #pragma unroll
    for (int j = 0; j < 16; j++) h[j] = fmaxf(acc[j], 0.f);
  }
  float* ag = agg + (long)d * 16;
  #pragma unroll
  for (int j = 0; j < 16; j++) atomicAdd(ag + j, h[j]);
  atomicAdd(cnt + d, 1.0f);
}

__global__ __launch_bounds__(256) void node_fin(float* __restrict__ x, const float* __restrict__ cnt)
{
  int i = blockIdx.x * 256 + threadIdx.x;
  if (i >= NNODES * CC) return;
  float c = cnt[i >> 4];
  x[i] = x[i] / fmaxf(c, 1.f);
}

// ===== dense layer: h (LDS, stride-49 slice) x W (uniform/scalar) -> back to LDS =====
template<int IN>
__device__ __forceinline__ void dense_to_lds(float* hl,
    const float* __restrict__ w, const float* __restrict__ b)
{
  float acc[HH];
  #pragma unroll
  for (int j = 0; j < HH; j++) acc[j] = b[j];
  #pragma unroll 8
  for (int k = 0; k < IN; k++){
    float v = hl[k];
    #pragma unroll
    for (int j = 0; j < HH; j++) acc[j] = fmaf(v, w[k*HH + j], acc[j]);
  }
  #pragma unroll
  for (int j = 0; j < HH; j++) hl[j] = fmaxf(acc[j], 0.f);
}

__device__ __forceinline__ void loadpair(const float* __restrict__ x, int a, int b, float* hl){
  const float4* pa = (const float4*)(x + (long)a * 16);
  const float4* pb = (const float4*)(x + (long)b * 16);
  #pragma unroll
  for (int i = 0; i < 4; i++){ float4 v = pa[i]; hl[4*i]=v.x; hl[4*i+1]=v.y; hl[4*i+2]=v.z; hl[4*i+3]=v.w; }
  #pragma unroll
  for (int i = 0; i < 4; i++){ float4 v = pb[i]; hl[16+4*i]=v.x; hl[16+4*i+1]=v.y; hl[16+4*i+2]=v.z; hl[16+4*i+3]=v.w; }
}

// ================= fused EdgeConv1 + EdgeConv2 (unchanged from r7) ==================
__global__ __launch_bounds__(256) void ec_kernel(
    const float* __restrict__ x1, const float* __restrict__ x2,
    const int* __restrict__ ei, const float* __restrict__ act,
    const float* __restrict__ e1w0, const float* __restrict__ e1b0,
    const float* __restrict__ e1wh, const float* __restrict__ e1bh,
    const float* __restrict__ e1wc, const float* __restrict__ e1bc,
    const float* __restrict__ e2w0, const float* __restrict__ e2b0,
    const float* __restrict__ e2wh, const float* __restrict__ e2bh,
    const float* __restrict__ e2wc, const float* __restrict__ e2bc,
    float* __restrict__ out, float* __restrict__ slacc)
{
  __shared__ float hbuf[256 * 49];
  float* hl = hbuf + threadIdx.x * 49;

  int e = blockIdx.x * 256 + threadIdx.x;
  bool valid = e < NEDGES;
  int e0 = valid ? e : (NEDGES - 1);
  int s = ei[e0];
  int d = ei[NEDGES + e0];

  float f1[HH], ef[HH];
  float side = 0.f;

  loadpair(x1, d, s, hl);
  dense_to_lds<32>(hl, e1w0, e1b0);
  for (int l = 0; l < NL; l++) dense_to_lds<48>(hl, e1wh + l*2304, e1bh + l*48);
  #pragma unroll
  for (int j = 0; j < HH; j++) f1[j] = hl[j];

  loadpair(x1, s, d, hl);
  dense_to_lds<32>(hl, e1w0, e1b0);
  for (int l = 0; l < NL; l++) dense_to_lds<48>(hl, e1wh + l*2304, e1bh + l*48);

  #pragma unroll
  for (int j = 0; j < HH; j++){
    float f2v = hl[j];
    float dd = f1[j] - f2v;
    side += dd * dd;
    hl[j] = 0.5f * (f1[j] + f2v);
  }
  {
    float a = act[e0];
    float acc[HH];
    #pragma unroll
    for (int j = 0; j < HH; j++) acc[j] = fmaf(a, e1wc[48*HH + j], e1bc[j]);
    #pragma unroll 8
    for (int k = 0; k < HH; k++){
      float v = hl[k];
      #pragma unroll
      for (int j = 0; j < HH; j++) acc[j] = fmaf(v, e1wc[k*HH + j], acc[j]);
    }
    #pragma unroll
    for (int j = 0; j < HH; j++) ef[j] = acc[j];
  }

  loadpair(x2, d, s, hl);
  dense_to_lds<32>(hl, e2w0, e2b0);
  for (int l = 0; l < NL; l++) dense_to_lds<48>(hl, e2wh + l*2304, e2bh + l*48);
  #pragma unroll
  for (int j = 0; j < HH; j++) f1[j] = hl[j];

  loadpair(x2, s, d, hl);
  dense_to_lds<32>(hl, e2w0, e2b0);
  for (int l = 0; l < NL; l++) dense_to_lds<48>(hl, e2wh + l*2304, e2bh + l*48);

  float o = e2bc[0];
  #pragma unroll
  for (int j = 0; j < HH; j++){
    float f2v = hl[j];
    float dd = f1[j] - f2v;
    side += dd * dd;
    float fe = 0.5f * (f1[j] + f2v);
    o = fmaf(fe, e2wc[j], o);
    o = fmaf(ef[j], e2wc[48 + j], o);
  }
  if (valid) out[e0] = o;

  if (!valid) side = 0.f;
  #pragma unroll
  for (int off = 32; off > 0; off >>= 1) side += __shfl_down(side, off);
  if ((threadIdx.x & 63) == 0) atomicAdd(slacc, side);
}

__global__ void fin_sl(const float* __restrict__ slacc, float* __restrict__ out){
  if (threadIdx.x == 0 && blockIdx.x == 0)
    out[NEDGES] = slacc[0] * (1.0f / 57600000.0f);
}

// ================= launch ==================
extern "C" void kernel_launch(void* const* d_in, const int* in_sizes, int n_in,
                              void* d_out, int out_size, void* d_ws, size_t ws_size,
                              hipStream_t stream)
{
  if (n_in < 25) return;

  const float* nf  = (const float*)d_in[0];
  const int*   ei  = (const int*)d_in[1];
  const float* ang = (const float*)d_in[2];
  const float* act = (const float*)d_in[4];
  const float* nc1_w0 = (const float*)d_in[5];
  const float* nc1_b0 = (const float*)d_in[6];
  const float* nc1_wh = (const float*)d_in[7];
  const float* nc1_bh = (const float*)d_in[8];
  const float* nc2_w0 = (const float*)d_in[9];
  const float* nc2_b0 = (const float*)d_in[10];
  const float* nc2_wh = (const float*)d_in[11];
  const float* nc2_bh = (const float*)d_in[12];
  const float* e1w0 = (const float*)d_in[13];
  const float* e1b0 = (const float*)d_in[14];
  const float* e1wh = (const float*)d_in[15];
  const float* e1bh = (const float*)d_in[16];
  const float* e1wc = (const float*)d_in[17];
  const float* e1bc = (const float*)d_in[18];
  const float* e2w0 = (const float*)d_in[19];
  const float* e2b0 = (const float*)d_in[20];
  const float* e2wh = (const float*)d_in[21];
  const float* e2bh = (const float*)d_in[22];
  const float* e2wc = (const float*)d_in[23];
  const float* e2bc = (const float*)d_in[24];

  float* ws  = (float*)d_ws;
  float* out = (float*)d_out;
  const int eb = (NEDGES + 255) / 256;       // 2344
  const int nbN = (NNODES + 255) / 256;      // 391

  if (ws_size >= (size_t)WS_CSR_FLOATS * sizeof(float)){
    // ======== CSR path: no scatter atomics in the MLP hot loop ========
    float* x1 = ws + OX1;
    float* x2 = ws + OX2;
    int* rowptr = (int*)(ws + OROW);
    int* deg    = (int*)(ws + ODEG);
    int* perm   = (int*)(ws + OPERM);
    float* sl   = ws + OSL;

    hipMemsetAsync(deg, 0, (size_t)NNODES * sizeof(int), stream);
    hipMemsetAsync(sl, 0, sizeof(float), stream);

    hipLaunchKernelGGL(count_deg, dim3(eb), dim3(256), 0, stream, ei, deg);
    hipLaunchKernelGGL(scan_deg, dim3(1), dim3(1024), 0, stream, deg, rowptr);
    hipMemsetAsync(deg, 0, (size_t)NNODES * sizeof(int), stream);
    hipLaunchKernelGGL(scatter_perm, dim3(eb), dim3(256), 0, stream, ei, rowptr, deg, perm);

    hipLaunchKernelGGL(nc_csr, dim3(nbN), dim3(256), 0, stream,
        nf, ei, ang, rowptr, perm, nc1_w0, nc1_b0, nc1_wh, nc1_bh, x1);
    hipLaunchKernelGGL(nc_csr, dim3(nbN), dim3(256), 0, stream,
        x1, ei, ang, rowptr, perm, nc2_w0, nc2_b0, nc2_wh, nc2_bh, x2);

    hipLaunchKernelGGL(ec_kernel, dim3(eb), dim3(256), 0, stream,
        x1, x2, ei, act,
        e1w0, e1b0, e1wh, e1bh, e1wc, e1bc,
        e2w0, e2b0, e2wh, e2bh, e2wc, e2bc,
        out, sl);
    hipLaunchKernelGGL(fin_sl, dim3(1), dim3(64), 0, stream, sl, out);
  } else if (ws_size >= (size_t)WS_ATOM_FLOATS * sizeof(float)){
    // ======== fallback: proven round-7 atomic path ========
    float* x1  = ws + OX1;
    float* x2  = ws + OX2;
    float* cnt = ws + FCNT;
    float* sl  = ws + FSL;
    const int nb = (NNODES * CC + 255) / 256;

    hipMemsetAsync(ws, 0, (size_t)WS_ATOM_FLOATS * sizeof(float), stream);
    hipLaunchKernelGGL(nc_kernel, dim3(eb), dim3(256), 0, stream,
        nf, ei, ang, nc1_w0, nc1_b0, nc1_wh, nc1_bh, x1, cnt);
    hipLaunchKernelGGL(node_fin, dim3(nb), dim3(256), 0, stream, x1, cnt);
    hipMemsetAsync(cnt, 0, (size_t)NNODES * sizeof(float), stream);
    hipLaunchKernelGGL(nc_kernel, dim3(eb), dim3(256), 0, stream,
        x1, ei, ang, nc2_w0, nc2_b0, nc2_wh, nc2_bh, x2, cnt);
    hipLaunchKernelGGL(node_fin, dim3(nb), dim3(256), 0, stream, x2, cnt);
    hipLaunchKernelGGL(ec_kernel, dim3(eb), dim3(256), 0, stream,
        x1, x2, ei, act,
        e1w0, e1b0, e1wh, e1bh, e1wc, e1bc,
        e2w0, e2b0, e2wh, e2bh, e2wc, e2bc,
        out, sl);
    hipLaunchKernelGGL(fin_sl, dim3(1), dim3(64), 0, stream, sl, out);
  }
}

// Round 9
// 1243.337 us; speedup vs baseline: 1.8931x; 1.4182x over previous
//
#include <hip/hip_runtime.h>

typedef _Float16 f16;
typedef __attribute__((ext_vector_type(8))) _Float16 f16x8;
typedef __attribute__((ext_vector_type(4))) float f32x4;

#define NNODES 100000
#define NEDGES 600000
#define CC 16
#define HH 48
#define NL 5

// ---- CSR ws layout (float-sized units), total 4,000,064 floats = 16.0 MB ----
#define OX1   0          // 1,600,000 f
#define OX2   1600000    // 1,600,000 f
#define OROW  3200000    // 100,001 int
#define ODEG  3300032    // 100,000 int
#define OPERM 3400032    // 600,000 int
#define OSL   4000032    // 1 f
#define WS_CSR_FLOATS    4000064
// ---- fallback (atomic) layout ----
#define FCNT  3200000
#define FSL   3300000
#define WS_ATOM_FLOATS   3300032

// =================== CSR build ===================
__global__ __launch_bounds__(256) void count_deg(const int* __restrict__ ei, int* __restrict__ deg){
  int e = blockIdx.x * 256 + threadIdx.x;
  if (e >= NEDGES) return;
  atomicAdd(&deg[ei[NEDGES + e]], 1);
}

__global__ __launch_bounds__(1024) void scan_deg(const int* __restrict__ deg, int* __restrict__ rowptr){
  __shared__ int part[1024];
  int t = threadIdx.x;
  const int CH = (NNODES + 1023) / 1024;
  int b = t * CH;
  int e = b + CH < NNODES ? b + CH : NNODES;
  int s = 0;
  for (int i = b; i < e; i++) s += deg[i];
  part[t] = s;
  __syncthreads();
  for (int off = 1; off < 1024; off <<= 1){
    int v = (t >= off) ? part[t - off] : 0;
    __syncthreads();
    part[t] += v;
    __syncthreads();
  }
  int run = (t == 0) ? 0 : part[t - 1];
  for (int i = b; i < e; i++){ rowptr[i] = run; run += deg[i]; }
  if (t == 1023) rowptr[NNODES] = run;
}

__global__ __launch_bounds__(256) void scatter_perm(const int* __restrict__ ei,
    const int* __restrict__ rowptr, int* __restrict__ deg2, int* __restrict__ perm){
  int e = blockIdx.x * 256 + threadIdx.x;
  if (e >= NEDGES) return;
  int d = ei[NEDGES + e];
  int pos = rowptr[d] + atomicAdd(&deg2[d], 1);
  perm[pos] = e;
}

// ============ NodeConv, node-parallel CSR (unchanged from r8) ============
__global__ __launch_bounds__(256) void nc_csr(
    const float* __restrict__ x, const int* __restrict__ ei,
    const float* __restrict__ ang,
    const int* __restrict__ rowptr, const int* __restrict__ perm,
    const float* __restrict__ w0, const float* __restrict__ b0,
    const float* __restrict__ wh, const float* __restrict__ bh,
    float* __restrict__ xout)
{
  int n = blockIdx.x * 256 + threadIdx.x;
  if (n >= NNODES) return;
  int beg = rowptr[n], end = rowptr[n + 1];

  float xd[16];
  {
    const float4* pd = (const float4*)(x + (long)n * 16);
    #pragma unroll
    for (int i = 0; i < 4; i++){ float4 v = pd[i]; xd[4*i]=v.x; xd[4*i+1]=v.y; xd[4*i+2]=v.z; xd[4*i+3]=v.w; }
  }
  float p0[16];
  #pragma unroll
  for (int j = 0; j < 16; j++) p0[j] = b0[j];
  #pragma unroll
  for (int k = 0; k < 16; k++){
    float v = xd[k];
    #pragma unroll
    for (int j = 0; j < 16; j++) p0[j] = fmaf(v, w0[k*16 + j], p0[j]);
  }

  float sum[16];
  #pragma unroll
  for (int j = 0; j < 16; j++) sum[j] = 0.f;

  for (int idx = beg; idx < end; idx++){
    int e = perm[idx];
    int s = ei[e];
    float a_ = ang[e];
    float xs[16];
    {
      const float4* ps = (const float4*)(x + (long)s * 16);
      #pragma unroll
      for (int i = 0; i < 4; i++){ float4 v = ps[i]; xs[4*i]=v.x; xs[4*i+1]=v.y; xs[4*i+2]=v.z; xs[4*i+3]=v.w; }
    }
    float acc[16], h[16];
    #pragma unroll
    for (int j = 0; j < 16; j++) acc[j] = p0[j];
    #pragma unroll
    for (int k = 0; k < 16; k++){
      float v = xs[k];
      #pragma unroll
      for (int j = 0; j < 16; j++) acc[j] = fmaf(v, w0[(16 + k)*16 + j], acc[j]);
    }
    #pragma unroll
    for (int j = 0; j < 16; j++) h[j] = fmaxf(fmaf(a_, w0[32*16 + j], acc[j]), 0.f);

    for (int l = 0; l < NL; l++){
      const float* w = wh + l * 256;
      const float* b = bh + l * 16;
      #pragma unroll
      for (int j = 0; j < 16; j++) acc[j] = b[j];
      #pragma unroll
      for (int k = 0; k < 16; k++){
        float v = h[k];
        #pragma unroll
        for (int j = 0; j < 16; j++) acc[j] = fmaf(v, w[k*16 + j], acc[j]);
      }
      #pragma unroll
      for (int j = 0; j < 16; j++) h[j] = fmaxf(acc[j], 0.f);
    }
    #pragma unroll
    for (int j = 0; j < 16; j++) sum[j] += h[j];
  }

  float inv = 1.f / fmaxf((float)(end - beg), 1.f);
  float4* po = (float4*)(xout + (long)n * 16);
  #pragma unroll
  for (int i = 0; i < 4; i++){
    float4 v; v.x = sum[4*i]*inv; v.y = sum[4*i+1]*inv; v.z = sum[4*i+2]*inv; v.w = sum[4*i+3]*inv;
    po[i] = v;
  }
}

// =================== fallback atomic NodeConv (r7, proven) ===================
__global__ __launch_bounds__(256) void nc_kernel(
    const float* __restrict__ x, const int* __restrict__ ei,
    const float* __restrict__ ang,
    const float* __restrict__ w0, const float* __restrict__ b0,
    const float* __restrict__ wh, const float* __restrict__ bh,
    float* __restrict__ agg, float* __restrict__ cnt)
{
  int e = blockIdx.x * 256 + threadIdx.x;
  if (e >= NEDGES) return;
  int s = ei[e];
  int d = ei[NEDGES + e];
  float in[33];
  {
    const float4* pd = (const float4*)(x + (long)d * 16);
    const float4* ps = (const float4*)(x + (long)s * 16);
    #pragma unroll
    for (int i = 0; i < 4; i++){ float4 v = pd[i]; in[4*i]=v.x; in[4*i+1]=v.y; in[4*i+2]=v.z; in[4*i+3]=v.w; }
    #pragma unroll
    for (int i = 0; i < 4; i++){ float4 v = ps[i]; in[16+4*i]=v.x; in[16+4*i+1]=v.y; in[16+4*i+2]=v.z; in[16+4*i+3]=v.w; }
  }
  in[32] = ang[e];
  float h[16], acc[16];
  #pragma unroll
  for (int j = 0; j < 16; j++) acc[j] = b0[j];
  #pragma unroll
  for (int k = 0; k < 33; k++){
    float v = in[k];
    #pragma unroll
    for (int j = 0; j < 16; j++) acc[j] = fmaf(v, w0[k*16+j], acc[j]);
  }
  #pragma unroll
  for (int j = 0; j < 16; j++) h[j] = fmaxf(acc[j], 0.f);
  for (int l = 0; l < NL; l++){
    const float* w = wh + l * 256;
    const float* b = bh + l * 16;
    #pragma unroll
    for (int j = 0; j < 16; j++) acc[j] = b[j];
    #pragma unroll
    for (int k = 0; k < 16; k++){
      float v = h[k];
      #pragma unroll
      for (int j = 0; j < 16; j++) acc[j] = fmaf(v, w[k*16+j], acc[j]);
    }
    #pragma unroll
    for (int j = 0; j < 16; j++) h[j] = fmaxf(acc[j], 0.f);
  }
  float* ag = agg + (long)d * 16;
  #pragma unroll
  for (int j = 0; j < 16; j++) atomicAdd(ag + j, h[j]);
  atomicAdd(cnt + d, 1.0f);
}

__global__ __launch_bounds__(256) void node_fin(float* __restrict__ x, const float* __restrict__ cnt)
{
  int i = blockIdx.x * 256 + threadIdx.x;
  if (i >= NNODES * CC) return;
  float c = cnt[i >> 4];
  x[i] = x[i] / fmaxf(c, 1.f);
}

// ============================================================================
// Fused EdgeConv1+EdgeConv2 via MFMA (fp16 in / fp32 accumulate).
// Block = 256 threads = 128 edges = 256 GEMM rows (row 2t = [x_d|x_s], 2t+1 = [x_s|x_d]).
// H: 256 rows x 72 halves LDS (K<=64, zero-padded; 16B-aligned rows).
// W^T: double-buffered 48x72 pane, staged from global per layer.
// ef: even rows only, 128 x 52 halves. Total LDS = 64000 B (2 blocks/CU).
// Fragment layouts per guide §3 (HW-verified m89/m120):
//   A[m=lane&15][k=quad*8+j], B[n=lane&15][k=quad*8+j], C col=lane&15 row=quad*4+reg.
// ============================================================================
__global__ __launch_bounds__(256) void ec_mfma(
    const float* __restrict__ x1, const float* __restrict__ x2,
    const int* __restrict__ ei, const float* __restrict__ act,
    const float* __restrict__ e1w0, const float* __restrict__ e1b0,
    const float* __restrict__ e1wh, const float* __restrict__ e1bh,
    const float* __restrict__ e1wc, const float* __restrict__ e1bc,
    const float* __restrict__ e2w0, const float* __restrict__ e2b0,
    const float* __restrict__ e2wh, const float* __restrict__ e2bh,
    const float* __restrict__ e2wc, const float* __restrict__ e2bc,
    float* __restrict__ out, float* __restrict__ slacc)
{
  __shared__ __align__(16) f16 Hb[256 * 72];     // 36864 B
  __shared__ __align__(16) f16 Wb[2][48 * 72];   // 13824 B
  __shared__ __align__(16) f16 EFb[128 * 52];    // 13312 B

  const int t = threadIdx.x;
  const int lane = t & 63;
  const int q = lane >> 4, n15 = lane & 15;
  const int wrow = (t >> 6) * 64;                // wave's 64-row base
  const int ebase = blockIdx.x * 128;
  const int o = t & 1;
  int e = ebase + (t >> 1);
  const bool valid = e < NEDGES;
  if (!valid) e = NEDGES - 1;
  const int s = ei[e], d = ei[NEDGES + e];
  const int nA = o ? s : d;                      // row 2t: [x_d|x_s]; 2t+1: [x_s|x_d]
  const int nB = o ? d : s;

  float side = 0.f;

  // ---- stage W^T[n][k] (fp16, stride 72) from global w[k*48+n], zero k>=Kl ----
  auto stage_w = [&](const float* w, int Kl, int buf){
    f16* dst = Wb[buf];
    for (int idx = t; idx < 48 * Kl; idx += 256){
      int k = idx / 48, n = idx - k * 48;        // coalesced global read w[idx]
      dst[n * 72 + k] = (f16)w[idx];
    }
    for (int idx = t; idx < 48 * (64 - Kl); idx += 256){
      int k = Kl + idx / 48, n = idx - (idx / 48) * 48;
      dst[n * 72 + k] = (f16)0.f;
    }
  };

  // ---- stage this thread's row of inputs (k0..31), zero k32..63 ----
  auto stage_x = [&](const float* x){
    const float4* pa = (const float4*)(x + (long)nA * 16);
    const float4* pb = (const float4*)(x + (long)nB * 16);
    float4 a0 = pa[0], a1 = pa[1], a2 = pa[2], a3 = pa[3];
    float4 b0 = pb[0], b1 = pb[1], b2 = pb[2], b3 = pb[3];
    f16* hp = &Hb[t * 72];
    f16x8 h;
    h[0]=(f16)a0.x; h[1]=(f16)a0.y; h[2]=(f16)a0.z; h[3]=(f16)a0.w;
    h[4]=(f16)a1.x; h[5]=(f16)a1.y; h[6]=(f16)a1.z; h[7]=(f16)a1.w;
    *(f16x8*)(hp + 0) = h;
    h[0]=(f16)a2.x; h[1]=(f16)a2.y; h[2]=(f16)a2.z; h[3]=(f16)a2.w;
    h[4]=(f16)a3.x; h[5]=(f16)a3.y; h[6]=(f16)a3.z; h[7]=(f16)a3.w;
    *(f16x8*)(hp + 8) = h;
    h[0]=(f16)b0.x; h[1]=(f16)b0.y; h[2]=(f16)b0.z; h[3]=(f16)b0.w;
    h[4]=(f16)b1.x; h[5]=(f16)b1.y; h[6]=(f16)b1.z; h[7]=(f16)b1.w;
    *(f16x8*)(hp + 16) = h;
    h[0]=(f16)b2.x; h[1]=(f16)b2.y; h[2]=(f16)b2.z; h[3]=(f16)b2.w;
    h[4]=(f16)b3.x; h[5]=(f16)b3.y; h[6]=(f16)b3.z; h[7]=(f16)b3.w;
    *(f16x8*)(hp + 24) = h;
    f16x8 z = {};
    *(f16x8*)(hp + 32) = z; *(f16x8*)(hp + 40) = z;
    *(f16x8*)(hp + 48) = z; *(f16x8*)(hp + 56) = z;
  };

  // ---- fe phase: rows t and t^1 (same wave) -> fe via shfl_xor; side accum ----
  auto fe_phase = [&](bool withAct){
    float sacc = 0.f;
    #pragma unroll 8
    for (int j = 0; j < 48; j++){
      float v = (float)Hb[t * 72 + j];
      float pv = __shfl_xor(v, 1);
      float dd = v - pv;
      sacc += dd * dd;
      Hb[t * 72 + j] = (f16)(0.5f * (v + pv));   // own-row write only: no cross-lane WAR
    }
    if (valid) side += sacc;
    if (withAct) Hb[t * 72 + 48] = (f16)act[e];  // k48 = action (wc1 row 48 handles it)
  };

  // ---- one dense layer: H(256xK) @ W(Kx48) -> H (or EFb for combine) ----
  auto compute_layer = [&](int buf, const float* bias, bool relu, bool toEF){
    const f16* Wl = Wb[buf];
    f32x4 C[4][3];
    #pragma unroll
    for (int mt = 0; mt < 4; mt++)
      #pragma unroll
      for (int nt = 0; nt < 3; nt++)
        C[mt][nt] = (f32x4){0.f, 0.f, 0.f, 0.f};
    #pragma unroll
    for (int ks = 0; ks < 2; ks++){
      f16x8 Bf[3];
      #pragma unroll
      for (int nt = 0; nt < 3; nt++)
        Bf[nt] = *(const f16x8*)&Wl[(16 * nt + n15) * 72 + ks * 32 + q * 8];
      #pragma unroll
      for (int mt = 0; mt < 4; mt++){
        f16x8 Af = *(const f16x8*)&Hb[(wrow + 16 * mt + n15) * 72 + ks * 32 + q * 8];
        #pragma unroll
        for (int nt = 0; nt < 3; nt++)
          C[mt][nt] = __builtin_amdgcn_mfma_f32_16x16x32_f16(Af, Bf[nt], C[mt][nt], 0, 0, 0);
      }
    }
    float bv[3];
    #pragma unroll
    for (int nt = 0; nt < 3; nt++) bv[nt] = bias[16 * nt + n15];
    #pragma unroll
    for (int mt = 0; mt < 4; mt++)
      #pragma unroll
      for (int nt = 0; nt < 3; nt++)
        #pragma unroll
        for (int reg = 0; reg < 4; reg++){
          float v = C[mt][nt][reg] + bv[nt];
          if (relu) v = fmaxf(v, 0.f);
          int row = wrow + 16 * mt + 4 * q + reg;
          if (!toEF)            Hb[row * 72 + 16 * nt + n15] = (f16)v;
          else if (!(reg & 1))  EFb[(row >> 1) * 52 + 16 * nt + n15] = (f16)v;  // even rows only (pairs identical)
        }
  };

  // ================= two convs =================
  for (int conv = 0; conv < 2; conv++){
    const float* xs  = conv ? x2 : x1;
    const float* w0  = conv ? e2w0 : e1w0;
    const float* b0_ = conv ? e2b0 : e1b0;
    const float* wh  = conv ? e2wh : e1wh;
    const float* bh  = conv ? e2bh : e1bh;

    __syncthreads();                 // previous phase done with Hb/Wb
    stage_x(xs);
    stage_w(w0, 32, 0);

    const int nlay = conv ? 6 : 7;   // conv0: 6 MLP layers + combine GEMM
    for (int l = 0; l < nlay; l++){
      __syncthreads();               // layer l-1 compute + layer l staging complete
      if (l + 1 < nlay){
        if (l + 1 <= 5) stage_w(wh + l * 2304, 48, (l + 1) & 1);
        else            stage_w(e1wc, 49, (l + 1) & 1);         // combine: wc1 (49x48)
      }
      if (!conv && l == 6){          // fe + act before combine GEMM
        fe_phase(true);
        __syncthreads();
      }
      const float* bias = (l == 0) ? b0_ : (l <= 5 ? bh + (l - 1) * 48 : e1bc);
      compute_layer(l & 1, bias, l <= 5, (!conv && l == 6));
    }
    if (conv == 1){ __syncthreads(); fe_phase(false); }
  }

  // ================= final: o = fe2.wc2[0:48] + ef.wc2[48:96] + bc2 =================
  __syncthreads();
  if (t < 128){
    int ee = ebase + t;
    if (ee < NEDGES){
      float oa = e2bc[0];
      #pragma unroll 8
      for (int j = 0; j < 48; j++){
        oa += (float)Hb[(2 * t) * 72 + j] * e2wc[j];
        oa += (float)EFb[t * 52 + j] * e2wc[48 + j];
      }
      out[ee] = oa;
    }
  }
  float sv = side;
  #pragma unroll
  for (int off = 32; off; off >>= 1) sv += __shfl_down(sv, off);
  if (lane == 0) atomicAdd(slacc, sv);
}

// S = 2*(S1+S2) over rows; side_loss = (S1/(48E)+S2/(48E))/2 = S/(192E)
__global__ void fin_sl(const float* __restrict__ slacc, float* __restrict__ out){
  if (threadIdx.x == 0 && blockIdx.x == 0)
    out[NEDGES] = slacc[0] * (1.0f / 115200000.0f);
}

// ================= launch ==================
extern "C" void kernel_launch(void* const* d_in, const int* in_sizes, int n_in,
                              void* d_out, int out_size, void* d_ws, size_t ws_size,
                              hipStream_t stream)
{
  if (n_in < 25) return;

  const float* nf  = (const float*)d_in[0];
  const int*   ei  = (const int*)d_in[1];
  const float* ang = (const float*)d_in[2];
  const float* act = (const float*)d_in[4];
  const float* nc1_w0 = (const float*)d_in[5];
  const float* nc1_b0 = (const float*)d_in[6];
  const float* nc1_wh = (const float*)d_in[7];
  const float* nc1_bh = (const float*)d_in[8];
  const float* nc2_w0 = (const float*)d_in[9];
  const float* nc2_b0 = (const float*)d_in[10];
  const float* nc2_wh = (const float*)d_in[11];
  const float* nc2_bh = (const float*)d_in[12];
  const float* e1w0 = (const float*)d_in[13];
  const float* e1b0 = (const float*)d_in[14];
  const float* e1wh = (const float*)d_in[15];
  const float* e1bh = (const float*)d_in[16];
  const float* e1wc = (const float*)d_in[17];
  const float* e1bc = (const float*)d_in[18];
  const float* e2w0 = (const float*)d_in[19];
  const float* e2b0 = (const float*)d_in[20];
  const float* e2wh = (const float*)d_in[21];
  const float* e2bh = (const float*)d_in[22];
  const float* e2wc = (const float*)d_in[23];
  const float* e2bc = (const float*)d_in[24];

  float* ws  = (float*)d_ws;
  float* out = (float*)d_out;
  const int eb  = (NEDGES + 255) / 256;   // 2344
  const int nbN = (NNODES + 255) / 256;   // 391
  const int ecb = (NEDGES + 127) / 128;   // 4688

  if (ws_size >= (size_t)WS_CSR_FLOATS * sizeof(float)){
    float* x1 = ws + OX1;
    float* x2 = ws + OX2;
    int* rowptr = (int*)(ws + OROW);
    int* deg    = (int*)(ws + ODEG);
    int* perm   = (int*)(ws + OPERM);
    float* sl   = ws + OSL;

    hipMemsetAsync(deg, 0, (size_t)NNODES * sizeof(int), stream);
    hipMemsetAsync(sl, 0, sizeof(float), stream);

    hipLaunchKernelGGL(count_deg, dim3(eb), dim3(256), 0, stream, ei, deg);
    hipLaunchKernelGGL(scan_deg, dim3(1), dim3(1024), 0, stream, deg, rowptr);
    hipMemsetAsync(deg, 0, (size_t)NNODES * sizeof(int), stream);
    hipLaunchKernelGGL(scatter_perm, dim3(eb), dim3(256), 0, stream, ei, rowptr, deg, perm);

    hipLaunchKernelGGL(nc_csr, dim3(nbN), dim3(256), 0, stream,
        nf, ei, ang, rowptr, perm, nc1_w0, nc1_b0, nc1_wh, nc1_bh, x1);
    hipLaunchKernelGGL(nc_csr, dim3(nbN), dim3(256), 0, stream,
        x1, ei, ang, rowptr, perm, nc2_w0, nc2_b0, nc2_wh, nc2_bh, x2);

    hipLaunchKernelGGL(ec_mfma, dim3(ecb), dim3(256), 0, stream,
        x1, x2, ei, act,
        e1w0, e1b0, e1wh, e1bh, e1wc, e1bc,
        e2w0, e2b0, e2wh, e2bh, e2wc, e2bc,
        out, sl);
    hipLaunchKernelGGL(fin_sl, dim3(1), dim3(64), 0, stream, sl, out);
  } else if (ws_size >= (size_t)WS_ATOM_FLOATS * sizeof(float)){
    float* x1  = ws + OX1;
    float* x2  = ws + OX2;
    float* cnt = ws + FCNT;
    float* sl  = ws + FSL;
    const int nb = (NNODES * CC + 255) / 256;

    hipMemsetAsync(ws, 0, (size_t)WS_ATOM_FLOATS * sizeof(float), stream);
    hipLaunchKernelGGL(nc_kernel, dim3(eb), dim3(256), 0, stream,
        nf, ei, ang, nc1_w0, nc1_b0, nc1_wh, nc1_bh, x1, cnt);
    hipLaunchKernelGGL(node_fin, dim3(nb), dim3(256), 0, stream, x1, cnt);
    hipMemsetAsync(cnt, 0, (size_t)NNODES * sizeof(float), stream);
    hipLaunchKernelGGL(nc_kernel, dim3(eb), dim3(256), 0, stream,
        x1, ei, ang, nc2_w0, nc2_b0, nc2_wh, nc2_bh, x2, cnt);
    hipLaunchKernelGGL(node_fin, dim3(nb), dim3(256), 0, stream, x2, cnt);
    hipLaunchKernelGGL(ec_mfma, dim3(ecb), dim3(256), 0, stream,
        x1, x2, ei, act,
        e1w0, e1b0, e1wh, e1bh, e1wc, e1bc,
        e2w0, e2b0, e2wh, e2bh, e2wc, e2bc,
        out, sl);
    hipLaunchKernelGGL(fin_sl, dim3(1), dim3(64), 0, stream, sl, out);
  }
}